// Round 8
// baseline (390.946 us; speedup 1.0000x reference)
//
#include <hip/hip_runtime.h>
#include <hip/hip_bf16.h>
#include <stdint.h>

// QLSTM: T=256, B=2048, DIN=128, NQ=16, 4 gates. fp32 inputs, fp32 outputs.
// R12: software-staggered dual chains (half-step offset).
//   - R11 diagnosis: chains phase-locked inside monolithic asm blocks (volatile
//     asm = scheduling barrier) -> both chains stall at the same trans/permlane
//     waits; wall ~1190cy/step vs ~400cy issue. Fix: chain B runs half a step
//     behind chain A: [A-dot asm]{A-cos+prefix || B-tail}[B-dot asm]{B-cos+prefix
//     || A-tail}. The asm dot blocks (17 inst) cover the other chain's latency;
//     the mixed C windows give the compiler two independent chains to weave.
//   - prefix product back to schedulable update_dpp intrinsics (R9 form).
//   - arithmetic per chain IDENTICAL to R11 -> absmax must stay 0.00390625.

#define T_STEPS 256
#define BATCH   2048
#define DIN     128
#define NQ      16
#define DTOT    144
#define NTILE   32          // 32 tiles of 8 timesteps
#define ZROW    66          // padded z row (floats)

typedef __attribute__((ext_vector_type(8))) short bf16x8;
typedef __attribute__((ext_vector_type(4))) float f32x4;
typedef __attribute__((ext_vector_type(2))) int   int2v;

#if defined(__has_builtin)
#if __has_builtin(__builtin_amdgcn_permlane16_swap) && __has_builtin(__builtin_amdgcn_permlane32_swap)
#define USE_PLSWAP 1
#endif
#endif
#ifndef USE_PLSWAP
#define USE_PLSWAP 0
#endif

__device__ __forceinline__ float bf2f(unsigned short u) {
    union { unsigned int i; float f; } v; v.i = ((unsigned int)u) << 16; return v.f;
}
__device__ __forceinline__ unsigned short f2bf(float f) {
    union { float f; unsigned int i; } v; v.f = f;
    unsigned int i = v.i;
    unsigned int r = i + 0x7fffu + ((i >> 16) & 1u);   // round-nearest-even
    return (unsigned short)(r >> 16);
}
__device__ __forceinline__ float ldval(const float* p) { return *p; }
__device__ __forceinline__ float ldval(const unsigned short* p) { return bf2f(*p); }

// ---------------- per-wave dtype detector (bf16=1, fp32=0), wave-uniform ----------------
__device__ __forceinline__ int detect_bf16(const unsigned int* __restrict__ xw, int lane) {
    int cnt = 0;
#pragma unroll
    for (int i = 0; i < 4; ++i) {
        unsigned int w = xw[lane + i * 64];
        unsigned int e = (w >> 7) & 0xFFu;
        cnt += (e >= 100u && e <= 140u) ? 1 : 0;
    }
#pragma unroll
    for (int d = 32; d > 0; d >>= 1) cnt += __shfl_down(cnt, d, 64);
    int tot = __shfl(cnt, 0, 64);
    return (tot >= 140) ? 1 : 0;
}

// ---------------- DPP helpers (schedulable intrinsics) ----------------
template <int CTRL>
__device__ __forceinline__ float dpp_sh(float v) {   // shift w/ multiplicative identity
    int r = __builtin_amdgcn_update_dpp(__builtin_bit_cast(int, 1.0f),
                                        __builtin_bit_cast(int, v),
                                        CTRL, 0xF, 0xF, false);
    return __builtin_bit_cast(float, r);
}

// ---------------- single-chain h-dot (asm-pinned, 17 inst) ----------------
__device__ __forceinline__ float dot1(float h, float cur, const float (&Wp)[16]) {
    float a0 = cur, a1, a2, a3;
    asm volatile(
        "s_nop 1\n\t"
        "v_fmac_f32 %0, %4, %5\n\t"
        "v_mul_f32_dpp %1, %4, %6 row_ror:4 row_mask:0xf bank_mask:0xf\n\t"
        "v_mul_f32_dpp %2, %4, %7 row_ror:8 row_mask:0xf bank_mask:0xf\n\t"
        "v_mul_f32_dpp %3, %4, %8 row_ror:12 row_mask:0xf bank_mask:0xf\n\t"
        "v_fmac_f32_dpp %0, %4, %9 row_ror:1 row_mask:0xf bank_mask:0xf\n\t"
        "v_fmac_f32_dpp %1, %4, %10 row_ror:5 row_mask:0xf bank_mask:0xf\n\t"
        "v_fmac_f32_dpp %2, %4, %11 row_ror:9 row_mask:0xf bank_mask:0xf\n\t"
        "v_fmac_f32_dpp %3, %4, %12 row_ror:13 row_mask:0xf bank_mask:0xf\n\t"
        "v_fmac_f32_dpp %0, %4, %13 row_ror:2 row_mask:0xf bank_mask:0xf\n\t"
        "v_fmac_f32_dpp %1, %4, %14 row_ror:6 row_mask:0xf bank_mask:0xf\n\t"
        "v_fmac_f32_dpp %2, %4, %15 row_ror:10 row_mask:0xf bank_mask:0xf\n\t"
        "v_fmac_f32_dpp %3, %4, %16 row_ror:14 row_mask:0xf bank_mask:0xf\n\t"
        "v_fmac_f32_dpp %0, %4, %17 row_ror:3 row_mask:0xf bank_mask:0xf\n\t"
        "v_fmac_f32_dpp %1, %4, %18 row_ror:7 row_mask:0xf bank_mask:0xf\n\t"
        "v_fmac_f32_dpp %2, %4, %19 row_ror:11 row_mask:0xf bank_mask:0xf\n\t"
        "v_fmac_f32_dpp %3, %4, %20 row_ror:15 row_mask:0xf bank_mask:0xf"
        : "+v"(a0), "=&v"(a1), "=&v"(a2), "=&v"(a3)
        : "v"(h), "v"(Wp[0]), "v"(Wp[4]), "v"(Wp[8]), "v"(Wp[12]),
          "v"(Wp[1]), "v"(Wp[5]), "v"(Wp[9]), "v"(Wp[13]),
          "v"(Wp[2]), "v"(Wp[6]), "v"(Wp[10]), "v"(Wp[14]),
          "v"(Wp[3]), "v"(Wp[7]), "v"(Wp[11]), "v"(Wp[15]));
    return (a0 + a1) + (a2 + a3);
}

// ---------------- cos + inclusive row-prefix product ----------------
template <int BASE>
__device__ __forceinline__ float cosprefix(float z) {
    float cz = __cosf(z);
    cz *= dpp_sh<BASE + 1>(cz);
    cz *= dpp_sh<BASE + 2>(cz);
    cz *= dpp_sh<BASE + 4>(cz);
    cz *= dpp_sh<BASE + 8>(cz);
    return cz;
}

// ---------------- gate exchange: s(row g) -> f/i/g/o at qubit n ----------------
__device__ __forceinline__ void gex(float s, bool m0, bool m1,
                                    int a_f, int a_i, int a_g, int a_o,
                                    float& fv, float& iv, float& gv, float& ov)
{
#if USE_PLSWAP
    int si = __builtin_bit_cast(int, s);
    int2v e1 = __builtin_amdgcn_permlane16_swap(si, si, false, false);
    int c1i = m0 ? e1[0] : e1[1];                       // row g^1
    int2v e2 = __builtin_amdgcn_permlane32_swap(si, si, false, false);
    int c2i = m1 ? e2[0] : e2[1];                       // row g^2
    int2v e3 = __builtin_amdgcn_permlane16_swap(c2i, c2i, false, false);
    int c3i = m0 ? e3[0] : e3[1];                       // row g^3
    float C0 = s;
    float C1 = __builtin_bit_cast(float, c1i);
    float C2 = __builtin_bit_cast(float, c2i);
    float C3 = __builtin_bit_cast(float, c3i);
    float P  = m1 ? C2 : C0;
    float Q  = m1 ? C3 : C1;
    float R_ = m1 ? C0 : C2;
    float S_ = m1 ? C1 : C3;
    fv = m0 ? Q  : P;
    iv = m0 ? P  : Q;
    gv = m0 ? S_ : R_;
    ov = m0 ? R_ : S_;
#else
    int si = __builtin_bit_cast(int, s);
    fv = __builtin_bit_cast(float, __builtin_amdgcn_ds_bpermute(a_f, si));
    iv = __builtin_bit_cast(float, __builtin_amdgcn_ds_bpermute(a_i, si));
    gv = __builtin_bit_cast(float, __builtin_amdgcn_ds_bpermute(a_g, si));
    ov = __builtin_bit_cast(float, __builtin_amdgcn_ds_bpermute(a_o, si));
#endif
}

// ---------------- per-chain step tail: nonlin + exchange + state update ----------------
__device__ __forceinline__ void tail1(int t, int g, int n, float cz,
                                      float& h, float& c, float& hs, int b,
                                      bool m0, bool m1,
                                      float kexp, float ksc, float koff,
                                      int a_f, int a_i, int a_g, int a_o,
                                      float* __restrict__ out)
{
    float e = __builtin_amdgcn_exp2f(cz * kexp);
    float rr = __builtin_amdgcn_rcpf(1.f + e);
    float s = fmaf(ksc, rr, koff);

    float fv, iv, gv, ov;
    gex(s, m0, m1, a_f, a_i, a_g, a_o, fv, iv, gv, ov);

    c = fmaf(fv, c, iv * gv);
    float e2 = __builtin_amdgcn_exp2f(c * -2.885390082f);
    float tc = fmaf(2.f, __builtin_amdgcn_rcpf(1.f + e2), -1.f);
    h = ov * tc;

    if ((t & 3) == g) hs = h;
    if ((t & 3) == 3)
        out[(size_t)(t - 3 + g) * (BATCH * NQ) + (size_t)b * NQ + n] = hs;
}

// ---------------- fused per-wave main (2 staggered chains / wave) ----------------
template <int BASE, typename InT>
__device__ __forceinline__ void fused_main(
    const InT* __restrict__ x, const InT* __restrict__ W,
    const InT* __restrict__ bv, const InT* __restrict__ th,
    float* __restrict__ out, int bA, int w, int lane,
    const float (&Wp)[16], float (*zt)[ZROW],
    bf16x8 (*wfh)[64], bf16x8 (*wfl)[64])
{
    const int m = lane & 15, quad = lane >> 4;
    const int g = quad, n = m;
    const int bB = bA + 1;
    const bool m0 = (g & 1) != 0, m1 = (g & 2) != 0;
    const float kexp = (g == 2) ? -2.885390082f : -1.442695041f;
    const float ksc  = (g == 2) ? 2.f : 1.f;
    const float koff = (g == 2) ? -1.f : 0.f;
    const int a_f = n << 2, a_i = (16 + n) << 2, a_g = (32 + n) << 2, a_o = (48 + n) << 2;

    // ---- cooperative W-fragment build: wave w handles k-tile kt = w ----
    if constexpr (sizeof(InT) == 2) {
#pragma unroll
        for (int nb = 0; nb < 4; ++nb)
            wfh[w * 4 + nb][lane] = *(const bf16x8*)((const unsigned short*)W +
                                    (size_t)(nb * 16 + m) * DTOT + w * 32 + quad * 8);
    } else {
#pragma unroll
        for (int nb = 0; nb < 4; ++nb) {
            const float* p = (const float*)W + (size_t)(nb * 16 + m) * DTOT + w * 32 + quad * 8;
            bf16x8 ah, al;
#pragma unroll
            for (int j = 0; j < 8; ++j) {
                float wv = p[j];
                unsigned short hh = f2bf(wv);
                ah[j] = (short)hh;
                al[j] = (short)f2bf(wv - bf2f(hh));
            }
            wfh[w * 4 + nb][lane] = ah;
            wfl[w * 4 + nb][lane] = al;
        }
    }
    const float bias = ldval(bv + lane) + ldval(th + lane);
    __syncthreads();            // the ONLY barrier; wf* read-only afterwards

    // A-row m -> x row (t = tl*8 + (m&7), batch = bA + (m>>3))
    const InT* xbase = x + ((size_t)(m & 7) * BATCH + (size_t)(bA + (m >> 3))) * DIN + quad * 8;

    f32x4 rx[8]; bf16x8 rbx[4];
    auto LOAD = [&](int tl) {
        const InT* p = xbase + (size_t)tl * ((size_t)8 * BATCH * DIN);
#pragma unroll
        for (int kt = 0; kt < 4; ++kt) {
            if constexpr (sizeof(InT) == 2) {
                rbx[kt] = *(const bf16x8*)(p + kt * 32);
            } else {
                rx[2 * kt]     = *(const f32x4*)((const float*)p + kt * 32);
                rx[2 * kt + 1] = *(const f32x4*)((const float*)p + kt * 32 + 4);
            }
        }
    };
    auto PRODUCE = [&]() {
        f32x4 acc[4] = {};
#pragma unroll
        for (int kt = 0; kt < 4; ++kt) {
            if constexpr (sizeof(InT) == 2) {
#pragma unroll
                for (int nb = 0; nb < 4; ++nb)
                    acc[nb] = __builtin_amdgcn_mfma_f32_16x16x32_bf16(rbx[kt], wfh[kt * 4 + nb][lane], acc[nb], 0, 0, 0);
            } else {
                bf16x8 ah, al;
#pragma unroll
                for (int j = 0; j < 8; ++j) {
                    float xv = rx[2 * kt + (j >> 2)][j & 3];
                    unsigned short hh = f2bf(xv);
                    ah[j] = (short)hh;
                    al[j] = (short)f2bf(xv - bf2f(hh));
                }
#pragma unroll
                for (int nb = 0; nb < 4; ++nb)
                    acc[nb] = __builtin_amdgcn_mfma_f32_16x16x32_bf16(ah, wfh[kt * 4 + nb][lane], acc[nb], 0, 0, 0);
#pragma unroll
                for (int nb = 0; nb < 4; ++nb)
                    acc[nb] = __builtin_amdgcn_mfma_f32_16x16x32_bf16(al, wfh[kt * 4 + nb][lane], acc[nb], 0, 0, 0);
#pragma unroll
                for (int nb = 0; nb < 4; ++nb)
                    acc[nb] = __builtin_amdgcn_mfma_f32_16x16x32_bf16(ah, wfl[kt * 4 + nb][lane], acc[nb], 0, 0, 0);
            }
        }
        // z[row = quad*4+r][col = nb*16+m]; rows 0..7 = batch A t0..7, 8..15 = batch B
#pragma unroll
        for (int nb = 0; nb < 4; ++nb)
#pragma unroll
            for (int r = 0; r < 4; ++r)
                zt[quad * 4 + r][nb * 16 + m] = acc[nb][r];
    };

    float hA = 0.f, cA = 0.f, hsA = 0.f;
    float hB = 0.f, cB = 0.f, hsB = 0.f;
    float zrA[8], zrB[8];

    LOAD(0);
    PRODUCE();          // zt := tile 0
    LOAD(1);
#pragma unroll
    for (int j = 0; j < 8; ++j) zrA[j] = zt[j][lane] + bias;
#pragma unroll
    for (int j = 0; j < 8; ++j) zrB[j] = zt[8 + j][lane] + bias;

    float zA = dot1(hA, zrA[0], Wp);    // A leads by half a step
    float czB = 0.f;                    // B's pending cumprod (none yet)

#pragma unroll 1
    for (int tl = 0; tl < NTILE; ++tl) {
        if (tl < NTILE - 1) PRODUCE();          // zt := tile tl+1 (tile tl already drained)
        if (tl < NTILE - 2) LOAD(tl + 2);
#pragma unroll
        for (int j = 0; j < 8; ++j) {
            const int t = tl * 8 + j;
            // window 1: A cos+prefix(t)  ||  B tail(t-1)
            float czA = cosprefix<BASE>(zA);
            if (j != 0 || tl != 0)
                tail1(t - 1, g, n, czB, hB, cB, hsB, bB, m0, m1,
                      kexp, ksc, koff, a_f, a_i, a_g, a_o, out);
            // B dot(t) (needs hB(t-1), just produced)
            float zB = dot1(hB, zrB[j], Wp);
            // window 2: B cos+prefix(t)  ||  A tail(t)
            czB = cosprefix<BASE>(zB);
            tail1(t, g, n, czA, hA, cA, hsA, bA, m0, m1,
                  kexp, ksc, koff, a_f, a_i, a_g, a_o, out);
            // A dot(t+1)
            if (j < 7) zA = dot1(hA, zrA[j + 1], Wp);
        }
        if (tl < NTILE - 1) {
            // drain next tile's z rows, then launch A's first dot of that tile
#pragma unroll
            for (int j = 0; j < 8; ++j) zrA[j] = zt[j][lane] + bias;
#pragma unroll
            for (int j = 0; j < 8; ++j) zrB[j] = zt[8 + j][lane] + bias;
            zA = dot1(hA, zrA[0], Wp);
        }
    }
    // epilogue: B finishes t = 255
    tail1(T_STEPS - 1, g, n, czB, hB, cB, hsB, bB, m0, m1,
          kexp, ksc, koff, a_f, a_i, a_g, a_o, out);

    if (g == 0) {
        out[(size_t)T_STEPS * BATCH * NQ + (size_t)bA * NQ + n] = hA;                      // hx
        out[(size_t)T_STEPS * BATCH * NQ + (size_t)BATCH * NQ + (size_t)bA * NQ + n] = cA; // cx
        out[(size_t)T_STEPS * BATCH * NQ + (size_t)bB * NQ + n] = hB;
        out[(size_t)T_STEPS * BATCH * NQ + (size_t)BATCH * NQ + (size_t)bB * NQ + n] = cB;
    }
}

__global__ __launch_bounds__(256, 1) void qlstm_fused(
    const void* __restrict__ x_, const void* __restrict__ W_,
    const void* __restrict__ b_, const void* __restrict__ th_,
    float* __restrict__ out)
{
    __shared__ float  zw[4][16][ZROW];      // 16.5 KiB: per-wave z tiles
    __shared__ bf16x8 wfh[16][64];          // 16 KiB: W hi fragments (shared)
    __shared__ bf16x8 wfl[16][64];          // 16 KiB: W lo fragments (fp32 path)

    const int lane = threadIdx.x & 63;
    const int w    = threadIdx.x >> 6;
    const int bA   = (blockIdx.x * 4 + w) * 2;
    const int n    = lane & 15;

    const int isbf = __builtin_amdgcn_readfirstlane(detect_bf16((const unsigned int*)x_, lane));

    // runtime probe of DPP row_ror direction (wave-uniform)
    int pr  = __builtin_amdgcn_update_dpp(0, lane, 0x121, 0xF, 0xF, false);
    int p0r = __shfl(pr, 0, 64);
    const int d = (p0r == 1) ? 1 : 15;

    float Wp[16];
    if (isbf) {
        const unsigned short* W = (const unsigned short*)W_;
#pragma unroll
        for (int k = 0; k < 16; ++k)
            Wp[k] = bf2f(W[(size_t)lane * DTOT + DIN + ((n + k * d) & 15)]);
    } else {
        const float* W = (const float*)W_;
#pragma unroll
        for (int k = 0; k < 16; ++k)
            Wp[k] = W[(size_t)lane * DTOT + DIN + ((n + k * d) & 15)];
    }

    // runtime probe of DPP row_shr direction (wave-uniform) for the prefix product
    int probe = __builtin_amdgcn_update_dpp(999, lane, 0x111, 0xF, 0xF, false);
    int p2 = __shfl(probe, 2, 64);

    if (isbf) {
        if (p2 == 1) fused_main<0x110, unsigned short>((const unsigned short*)x_, (const unsigned short*)W_,
                                                       (const unsigned short*)b_, (const unsigned short*)th_,
                                                       out, bA, w, lane, Wp, zw[w], wfh, wfl);
        else         fused_main<0x100, unsigned short>((const unsigned short*)x_, (const unsigned short*)W_,
                                                       (const unsigned short*)b_, (const unsigned short*)th_,
                                                       out, bA, w, lane, Wp, zw[w], wfh, wfl);
    } else {
        if (p2 == 1) fused_main<0x110, float>((const float*)x_, (const float*)W_,
                                              (const float*)b_, (const float*)th_,
                                              out, bA, w, lane, Wp, zw[w], wfh, wfl);
        else         fused_main<0x100, float>((const float*)x_, (const float*)W_,
                                              (const float*)b_, (const float*)th_,
                                              out, bA, w, lane, Wp, zw[w], wfh, wfl);
    }
}

extern "C" void kernel_launch(void* const* d_in, const int* in_sizes, int n_in,
                              void* d_out, int out_size, void* d_ws, size_t ws_size,
                              hipStream_t stream) {
    const void* x  = d_in[0];
    const void* W  = d_in[1];
    const void* bv = d_in[2];
    const void* th = d_in[3];
    (void)d_ws; (void)ws_size;
    qlstm_fused<<<BATCH / 8, 256, 0, stream>>>(x, W, bv, th, (float*)d_out);
}